// Round 12
// baseline (180.044 us; speedup 1.0000x reference)
//
#include <hip/hip_runtime.h>
#include <hip/hip_bf16.h>
#include <math.h>

// ---------------------------------------------------------------------------
// out[s] = (sum_i gate_i * x_i) @ Wm + (sum_i gate_i) * bm
// gate_i = softmax-with-eps over h_i = x_i.Wg + bg + pow*ln(w_i)
// index is SORTED -> segments are contiguous row ranges.
// R12 = R11 + NON-TEMPORAL loads of x (test: L3-hit-path bandwidth theory).
// ---------------------------------------------------------------------------

// K1: seg_start[s] = first row i with index[i] >= s ; seg_start[S] = N
__global__ __launch_bounds__(256) void k1_seg_offsets(const int* __restrict__ index,
                                                      int* __restrict__ seg_start,
                                                      int N, int S) {
    int tid = blockIdx.x * blockDim.x + threadIdx.x;
    int stride = gridDim.x * blockDim.x;
    for (int i = tid; i < N; i += stride) {
        int cur  = index[i];
        int prev = (i == 0) ? -1 : index[i - 1];
        for (int s = prev + 1; s <= cur; ++s) seg_start[s] = i;
        if (i == N - 1) {
            for (int s = cur + 1; s <= S; ++s) seg_start[s] = N;
        }
    }
}

typedef float f4v __attribute__((ext_vector_type(4)));

__device__ __forceinline__ float4 ld_nt4(const float* p) {
    f4v v = __builtin_nontemporal_load(reinterpret_cast<const f4v*>(p));
    return make_float4(v[0], v[1], v[2], v[3]);
}

// K2: one wave per segment (oversubscribed grid -> HW self-balancing).
// Wave = 4 groups x 16 lanes; one row per group per step (float8/lane).
// 2-deep prefetch, CLAMPED UNCONDITIONAL loads; predicate at compute.
// x loads are NON-TEMPORAL (nt): stream past L2/L3, no-allocate.
// Per-group online softmax with defer-rescale (THR=8); flash-combine per seg.
__global__ __launch_bounds__(256) void k2_seg_softmax_pool(
    const float* __restrict__ x, const float* __restrict__ wt,
    const float* __restrict__ Wg, const float* __restrict__ bg,
    const float* __restrict__ pw_, const int* __restrict__ seg_start,
    float* __restrict__ t, float* __restrict__ sgate, int S) {
    int gwid = (int)((blockIdx.x * 256 + threadIdx.x) >> 6);
    if (gwid >= S) return;
    int lane = threadIdx.x & 63;
    int grp  = lane >> 4;        // which row of the 4-row step
    int pos  = lane & 15;        // feature slice [8*pos, 8*pos+8)

    int start = seg_start[gwid], end = seg_start[gwid + 1];

    if (start >= end) {          // empty segment: exact zeros
        if (lane < 16) {
            float* tp = t + (size_t)gwid * 128 + pos * 8;
            *reinterpret_cast<float4*>(tp)     = make_float4(0.f, 0.f, 0.f, 0.f);
            *reinterpret_cast<float4*>(tp + 4) = make_float4(0.f, 0.f, 0.f, 0.f);
        }
        if (lane == 0) sgate[gwid] = 0.f;
        return;
    }

    float4 wg0 = *reinterpret_cast<const float4*>(Wg + pos * 8);
    float4 wg1 = *reinterpret_cast<const float4*>(Wg + pos * 8 + 4);
    float bgv = bg[0];
    float pw  = pw_[0];

    int nsteps = (end - start + 3) >> 2;
    int last   = end - 1;

    float4 a0, b0, a1, b1, a2, b2;
    float  w0, w1, w2;

    // clamped unconditional issue for step s (nt on the two x loads)
    auto issue = [&](int s, float4& A, float4& B, float& Wv) {
        int r  = start + 4 * s + grp;
        int rc = (r < last) ? r : last;           // clamp: always valid
        const float* p = x + (size_t)rc * 128 + pos * 8;
        A  = ld_nt4(p);
        B  = ld_nt4(p + 4);
        Wv = wt[rc];
    };

    issue(0, a0, b0, w0);
    issue(1, a1, b1, w1);

    float mg = -INFINITY, ssum = 0.f;
    float acc[8];
    #pragma unroll
    for (int j = 0; j < 8; ++j) acc[j] = 0.f;

    for (int s = 0; s < nsteps; ++s) {
        issue(s + 2, a2, b2, w2);     // clamped beyond end: harmless

        bool v = (start + 4 * s + grp) < end;
        // lw computed in parallel with the shfl-reduce chain (independent)
        float lw = fmaf(pw, __logf(w0), bgv);
        float p = a0.x*wg0.x + a0.y*wg0.y + a0.z*wg0.z + a0.w*wg0.w
                + b0.x*wg1.x + b0.y*wg1.y + b0.z*wg1.z + b0.w*wg1.w;
        p += __shfl_xor(p, 1);
        p += __shfl_xor(p, 2);
        p += __shfl_xor(p, 4);
        p += __shfl_xor(p, 8);
        float h = v ? (p + lw) : -1e30f;

        if (v && h > mg + 8.f) {          // defer-rescale: rarely taken
            float sc = __expf(mg - h);    // mg=-inf first time -> 0
            ssum *= sc;
            #pragma unroll
            for (int j = 0; j < 8; ++j) acc[j] *= sc;
            mg = h;
        }
        float e = v ? __expf(h - mg) : 0.f;   // bounded by e^8
        ssum += e;
        acc[0] += e * a0.x; acc[1] += e * a0.y; acc[2] += e * a0.z; acc[3] += e * a0.w;
        acc[4] += e * b0.x; acc[5] += e * b0.y; acc[6] += e * b0.z; acc[7] += e * b0.w;

        a0 = a1; b0 = b1; w0 = w1;
        a1 = a2; b1 = b2; w1 = w2;
    }

    // flash-combine the 4 groups (xor 16, then 32)
    #pragma unroll
    for (int off = 16; off <= 32; off <<= 1) {
        float mo = __shfl_xor(mg, off);
        float so = __shfl_xor(ssum, off);
        float ao[8];
        #pragma unroll
        for (int j = 0; j < 8; ++j) ao[j] = __shfl_xor(acc[j], off);
        float mc = fmaxf(mg, mo);
        float c1 = (mg > -1e37f) ? __expf(mg - mc) : 0.f;   // -inf guard
        float c2 = (mo > -1e37f) ? __expf(mo - mc) : 0.f;
        ssum = ssum * c1 + so * c2;
        #pragma unroll
        for (int j = 0; j < 8; ++j) acc[j] = acc[j] * c1 + ao[j] * c2;
        mg = mc;
    }

    float inv = 1.f / (ssum + 1e-10f);
    if (lane < 16) {
        float* tp = t + (size_t)gwid * 128 + pos * 8;
        *reinterpret_cast<float4*>(tp) =
            make_float4(acc[0]*inv, acc[1]*inv, acc[2]*inv, acc[3]*inv);
        *reinterpret_cast<float4*>(tp + 4) =
            make_float4(acc[4]*inv, acc[5]*inv, acc[6]*inv, acc[7]*inv);
    }
    if (lane == 0) sgate[gwid] = ssum * inv;   // sum of normalized gates
}

// K3: out[row][:] = t[row][:] @ Wm + sgate[row] * bm
// 512 threads: 8 waves x 8 rows = 64 rows/block; Wm staged once in 64 KiB LDS.
__global__ __launch_bounds__(512) void k3_out_gemm(
    const float* __restrict__ t, const float* __restrict__ Wm,
    const float* __restrict__ bm, const float* __restrict__ sgate,
    float* __restrict__ out, int S) {
    __shared__ float2 lwm[128][64];   // lwm[k][l] = (Wm[k][l], Wm[k][l+64])
    int tid = threadIdx.x;
    for (int idx = tid; idx < 128 * 64; idx += 512) {
        int k = idx >> 6, l = idx & 63;
        lwm[k][l] = make_float2(Wm[k * 128 + l], Wm[k * 128 + 64 + l]);
    }
    __syncthreads();

    int wave = tid >> 6, lane = tid & 63;
    int row0 = (blockIdx.x * 8 + wave) * 8;       // 8 rows per wave
    if (row0 >= S) return;

    const float* tb = t + (size_t)__builtin_amdgcn_readfirstlane(row0) * 128;

    float accx[8], accy[8];
    #pragma unroll
    for (int r = 0; r < 8; ++r) { accx[r] = 0.f; accy[r] = 0.f; }

    for (int k = 0; k < 128; k += 4) {
        float2 w0 = lwm[k][lane],     w1 = lwm[k + 1][lane];
        float2 w2 = lwm[k + 2][lane], w3 = lwm[k + 3][lane];
        #pragma unroll
        for (int r = 0; r < 8; ++r) {
            const float* tr = tb + r * 128 + k;   // uniform -> s_load
            float t0 = tr[0], t1 = tr[1], t2 = tr[2], t3 = tr[3];
            accx[r] += t0 * w0.x; accy[r] += t0 * w0.y;
            accx[r] += t1 * w1.x; accy[r] += t1 * w1.y;
            accx[r] += t2 * w2.x; accy[r] += t2 * w2.y;
            accx[r] += t3 * w3.x; accy[r] += t3 * w3.y;
        }
    }

    float bmx = bm[lane], bmy = bm[lane + 64];
    #pragma unroll
    for (int r = 0; r < 8; ++r) {
        int row = row0 + r;
        if (row < S) {
            float sg = sgate[row];
            out[(size_t)row * 128 + lane]      = accx[r] + sg * bmx;
            out[(size_t)row * 128 + lane + 64] = accy[r] + sg * bmy;
        }
    }
}

extern "C" void kernel_launch(void* const* d_in, const int* in_sizes, int n_in,
                              void* d_out, int out_size, void* d_ws, size_t ws_size,
                              hipStream_t stream) {
    const float* x       = (const float*)d_in[0];
    const float* weights = (const float*)d_in[1];
    const float* Wg      = (const float*)d_in[2];
    const float* bg      = (const float*)d_in[3];
    const float* Wm      = (const float*)d_in[4];
    const float* bm      = (const float*)d_in[5];
    const float* pow_    = (const float*)d_in[6];
    const int*   index   = (const int*)d_in[7];
    float* out = (float*)d_out;

    int N = in_sizes[1];          // weights is [N,1]
    int S = out_size / 128;       // out is [S,128]

    // workspace layout
    char* ws = (char*)d_ws;
    int* seg_start = (int*)ws;                                  // (S+1) ints
    size_t off = (((size_t)(S + 1) * 4) + 255) & ~(size_t)255;
    float* sgate = (float*)(ws + off);                          // S floats
    off += (((size_t)S * 4) + 255) & ~(size_t)255;
    float* t = (float*)(ws + off);                              // (S+64)*128 floats (pad for K3 over-read)

    k1_seg_offsets<<<2048, 256, 0, stream>>>(index, seg_start, N, S);
    k2_seg_softmax_pool<<<(S + 3) / 4, 256, 0, stream>>>(x, weights, Wg, bg, pow_,
                                                         seg_start, t, sgate, S);
    k3_out_gemm<<<(S + 63) / 64, 512, 0, stream>>>(t, Wm, bm, sgate, out, S);
}

// Round 13
// 128.314 us; speedup vs baseline: 1.4032x; 1.4032x over previous
//
#include <hip/hip_runtime.h>
#include <hip/hip_bf16.h>
#include <math.h>

// ---------------------------------------------------------------------------
// out[s] = (sum_i gate_i * x_i) @ Wm + (sum_i gate_i) * bm
// gate_i = softmax-with-eps over h_i = x_i.Wg + bg + pow*ln(w_i)
// index is SORTED -> segments are contiguous row ranges.
// R13 = R11 (K1/K2 verbatim) + K3 rewritten as bf16 MFMA GEMM.
// ---------------------------------------------------------------------------

typedef __attribute__((ext_vector_type(8))) short bf16x8;
typedef __attribute__((ext_vector_type(4))) float f32x4;

__device__ __forceinline__ short bfc(float f) {
    __hip_bfloat16 h = __float2bfloat16(f);
    return *reinterpret_cast<short*>(&h);
}

// K1: seg_start[s] = first row i with index[i] >= s ; seg_start[S] = N.
// Block 0 additionally packs Wm into B-fragment-ordered bf16 (32 KB):
// wpk[((kt*8+ct)*64 + lane)*8 + j] = bf16(Wm[kt*32+(lane>>4)*8+j][ct*16+(lane&15)])
__global__ __launch_bounds__(256) void k1_seg_offsets(const int* __restrict__ index,
                                                      int* __restrict__ seg_start,
                                                      const float* __restrict__ Wm,
                                                      unsigned short* __restrict__ wpk,
                                                      int N, int S) {
    if (blockIdx.x == 0) {
        for (int g = threadIdx.x; g < 2048; g += 256) {   // g=(kt*8+ct)*64+lane
            int lane = g & 63;
            int tile = g >> 6;
            int kt = tile >> 3, ct = tile & 7;
            int kbase = kt * 32 + (lane >> 4) * 8;
            int col   = ct * 16 + (lane & 15);
            #pragma unroll
            for (int j = 0; j < 8; ++j)
                wpk[g * 8 + j] = (unsigned short)bfc(Wm[(size_t)(kbase + j) * 128 + col]);
        }
    }
    int tid = blockIdx.x * blockDim.x + threadIdx.x;
    int stride = gridDim.x * blockDim.x;
    for (int i = tid; i < N; i += stride) {
        int cur  = index[i];
        int prev = (i == 0) ? -1 : index[i - 1];
        for (int s = prev + 1; s <= cur; ++s) seg_start[s] = i;
        if (i == N - 1) {
            for (int s = cur + 1; s <= S; ++s) seg_start[s] = N;
        }
    }
}

// K2: one wave per segment (oversubscribed grid -> HW self-balancing).
// R6-proven core, byte-for-byte.
__global__ __launch_bounds__(256) void k2_seg_softmax_pool(
    const float* __restrict__ x, const float* __restrict__ wt,
    const float* __restrict__ Wg, const float* __restrict__ bg,
    const float* __restrict__ pw_, const int* __restrict__ seg_start,
    float* __restrict__ t, float* __restrict__ sgate, int S) {
    int gwid = (int)((blockIdx.x * 256 + threadIdx.x) >> 6);
    if (gwid >= S) return;
    int lane = threadIdx.x & 63;
    int grp  = lane >> 4;        // which row of the 4-row step
    int pos  = lane & 15;        // feature slice [8*pos, 8*pos+8)

    int start = seg_start[gwid], end = seg_start[gwid + 1];

    if (start >= end) {          // empty segment: exact zeros
        if (lane < 16) {
            float* tp = t + (size_t)gwid * 128 + pos * 8;
            *reinterpret_cast<float4*>(tp)     = make_float4(0.f, 0.f, 0.f, 0.f);
            *reinterpret_cast<float4*>(tp + 4) = make_float4(0.f, 0.f, 0.f, 0.f);
        }
        if (lane == 0) sgate[gwid] = 0.f;
        return;
    }

    float4 wg0 = *reinterpret_cast<const float4*>(Wg + pos * 8);
    float4 wg1 = *reinterpret_cast<const float4*>(Wg + pos * 8 + 4);
    float bgv = bg[0];
    float pw  = pw_[0];

    int nsteps = (end - start + 3) >> 2;
    int last   = end - 1;

    float4 a0, b0, a1, b1, a2, b2;
    float  w0, w1, w2;

    auto issue = [&](int s, float4& A, float4& B, float& Wv) {
        int r  = start + 4 * s + grp;
        int rc = (r < last) ? r : last;           // clamp: always valid
        const float* p = x + (size_t)rc * 128 + pos * 8;
        A  = *reinterpret_cast<const float4*>(p);
        B  = *reinterpret_cast<const float4*>(p + 4);
        Wv = wt[rc];
    };

    issue(0, a0, b0, w0);
    issue(1, a1, b1, w1);

    float mg = -INFINITY, ssum = 0.f;
    float acc[8];
    #pragma unroll
    for (int j = 0; j < 8; ++j) acc[j] = 0.f;

    for (int s = 0; s < nsteps; ++s) {
        issue(s + 2, a2, b2, w2);     // clamped beyond end: harmless L1 hit

        bool v = (start + 4 * s + grp) < end;
        float lw = fmaf(pw, __logf(w0), bgv);
        float p = a0.x*wg0.x + a0.y*wg0.y + a0.z*wg0.z + a0.w*wg0.w
                + b0.x*wg1.x + b0.y*wg1.y + b0.z*wg1.z + b0.w*wg1.w;
        p += __shfl_xor(p, 1);
        p += __shfl_xor(p, 2);
        p += __shfl_xor(p, 4);
        p += __shfl_xor(p, 8);
        float h = v ? (p + lw) : -1e30f;

        if (v && h > mg + 8.f) {          // defer-rescale: rarely taken
            float sc = __expf(mg - h);
            ssum *= sc;
            #pragma unroll
            for (int j = 0; j < 8; ++j) acc[j] *= sc;
            mg = h;
        }
        float e = v ? __expf(h - mg) : 0.f;   // bounded by e^8
        ssum += e;
        acc[0] += e * a0.x; acc[1] += e * a0.y; acc[2] += e * a0.z; acc[3] += e * a0.w;
        acc[4] += e * b0.x; acc[5] += e * b0.y; acc[6] += e * b0.z; acc[7] += e * b0.w;

        a0 = a1; b0 = b1; w0 = w1;
        a1 = a2; b1 = b2; w1 = w2;
    }

    #pragma unroll
    for (int off = 16; off <= 32; off <<= 1) {
        float mo = __shfl_xor(mg, off);
        float so = __shfl_xor(ssum, off);
        float ao[8];
        #pragma unroll
        for (int j = 0; j < 8; ++j) ao[j] = __shfl_xor(acc[j], off);
        float mc = fmaxf(mg, mo);
        float c1 = (mg > -1e37f) ? __expf(mg - mc) : 0.f;
        float c2 = (mo > -1e37f) ? __expf(mo - mc) : 0.f;
        ssum = ssum * c1 + so * c2;
        #pragma unroll
        for (int j = 0; j < 8; ++j) acc[j] = acc[j] * c1 + ao[j] * c2;
        mg = mc;
    }

    float inv = 1.f / (ssum + 1e-10f);
    if (lane < 16) {
        float* tp = t + (size_t)gwid * 128 + pos * 8;
        *reinterpret_cast<float4*>(tp) =
            make_float4(acc[0]*inv, acc[1]*inv, acc[2]*inv, acc[3]*inv);
        *reinterpret_cast<float4*>(tp + 4) =
            make_float4(acc[4]*inv, acc[5]*inv, acc[6]*inv, acc[7]*inv);
    }
    if (lane == 0) sgate[gwid] = ssum * inv;
}

// K3 (MFMA): out = t @ Wm + sgate (x) bm, bf16 inputs, fp32 accumulate.
// Block = 256 threads = 4 waves; block covers 64 rows; wave w covers rows
// [blk*64+16w, +16). Per wave: kt-loop (4 K-chunks of 32): load A-frag from t
// (8 consecutive fp32 -> bf16), then 8 MFMAs (one per 16-col tile) from wpk.
// A layout: row=lane&15, k=kt*32+(lane>>4)*8+j. C/D: col=lane&15,
// row=(lane>>4)*4+reg (m89-verified).
__global__ __launch_bounds__(256) void k3_mfma(
    const float* __restrict__ t, const unsigned short* __restrict__ wpk,
    const float* __restrict__ bm, const float* __restrict__ sgate,
    float* __restrict__ out, int S) {
    int wv = threadIdx.x >> 6, lane = threadIdx.x & 63;
    int r0 = blockIdx.x * 64 + wv * 16;
    int arow = r0 + (lane & 15);
    int koff = (lane >> 4) * 8;

    f32x4 acc[8];
    #pragma unroll
    for (int ct = 0; ct < 8; ++ct) acc[ct] = (f32x4){0.f, 0.f, 0.f, 0.f};

    #pragma unroll
    for (int kt = 0; kt < 4; ++kt) {
        const float* ap = t + (size_t)arow * 128 + kt * 32 + koff;
        float4 a0 = *reinterpret_cast<const float4*>(ap);
        float4 a1 = *reinterpret_cast<const float4*>(ap + 4);
        bf16x8 af;
        af[0] = bfc(a0.x); af[1] = bfc(a0.y); af[2] = bfc(a0.z); af[3] = bfc(a0.w);
        af[4] = bfc(a1.x); af[5] = bfc(a1.y); af[6] = bfc(a1.z); af[7] = bfc(a1.w);
        #pragma unroll
        for (int ct = 0; ct < 8; ++ct) {
            bf16x8 bf_ = *reinterpret_cast<const bf16x8*>(
                wpk + ((size_t)((kt * 8 + ct) * 64 + lane)) * 8);
            acc[ct] = __builtin_amdgcn_mfma_f32_16x16x32_bf16(af, bf_, acc[ct], 0, 0, 0);
        }
    }

    // epilogue: + sgate[row]*bm[col]; guard row < S on store
    float sgv[4];
    #pragma unroll
    for (int reg = 0; reg < 4; ++reg)
        sgv[reg] = sgate[r0 + (lane >> 4) * 4 + reg];   // OOB rows read ws pad (finite, discarded)
    int colb = lane & 15;
    #pragma unroll
    for (int ct = 0; ct < 8; ++ct) {
        float bmv = bm[ct * 16 + colb];
        #pragma unroll
        for (int reg = 0; reg < 4; ++reg) {
            int row = r0 + (lane >> 4) * 4 + reg;
            if (row < S)
                out[(size_t)row * 128 + ct * 16 + colb] = acc[ct][reg] + sgv[reg] * bmv;
        }
    }
}

extern "C" void kernel_launch(void* const* d_in, const int* in_sizes, int n_in,
                              void* d_out, int out_size, void* d_ws, size_t ws_size,
                              hipStream_t stream) {
    const float* x       = (const float*)d_in[0];
    const float* weights = (const float*)d_in[1];
    const float* Wg      = (const float*)d_in[2];
    const float* bg      = (const float*)d_in[3];
    const float* Wm      = (const float*)d_in[4];
    const float* bm      = (const float*)d_in[5];
    const float* pow_    = (const float*)d_in[6];
    const int*   index   = (const int*)d_in[7];
    float* out = (float*)d_out;

    int N = in_sizes[1];          // weights is [N,1]
    int S = out_size / 128;       // out is [S,128]

    // workspace layout
    char* ws = (char*)d_ws;
    int* seg_start = (int*)ws;                                  // (S+1) ints
    size_t off = (((size_t)(S + 1) * 4) + 255) & ~(size_t)255;
    float* sgate = (float*)(ws + off);                          // S floats
    off += (((size_t)S * 4) + 255) & ~(size_t)255;
    float* t = (float*)(ws + off);                              // (S+64)*128 floats (pad for K3 over-read)
    off += (((size_t)(S + 64) * 128 * 4) + 255) & ~(size_t)255;
    unsigned short* wpk = (unsigned short*)(ws + off);          // 16384 bf16 (32 KB)

    k1_seg_offsets<<<2048, 256, 0, stream>>>(index, seg_start, Wm, wpk, N, S);
    k2_seg_softmax_pool<<<(S + 3) / 4, 256, 0, stream>>>(x, weights, Wg, bg, pow_,
                                                         seg_start, t, sgate, S);
    k3_mfma<<<(S + 63) / 64, 256, 0, stream>>>(t, wpk, bm, sgate, out, S);
}

// Round 14
// 124.219 us; speedup vs baseline: 1.4494x; 1.0330x over previous
//
#include <hip/hip_runtime.h>
#include <hip/hip_bf16.h>
#include <math.h>

// ---------------------------------------------------------------------------
// out[s] = (sum_i gate_i * x_i) @ Wm + (sum_i gate_i) * bm
// gate_i = softmax-with-eps over h_i = x_i.Wg + bg + pow*ln(w_i)
// index is SORTED -> segments are contiguous row ranges.
// R14 = R13 with t stored as bf16 (K3 converted t to bf16 anyway -> free).
// ---------------------------------------------------------------------------

typedef __attribute__((ext_vector_type(8))) short bf16x8;
typedef __attribute__((ext_vector_type(4))) float f32x4;

__device__ __forceinline__ short bfc(float f) {
    __hip_bfloat16 h = __float2bfloat16(f);
    return *reinterpret_cast<short*>(&h);
}

// K1: seg_start[s] = first row i with index[i] >= s ; seg_start[S] = N.
// Block 0 additionally packs Wm into B-fragment-ordered bf16 (32 KB):
// wpk[((kt*8+ct)*64 + lane)*8 + j] = bf16(Wm[kt*32+(lane>>4)*8+j][ct*16+(lane&15)])
__global__ __launch_bounds__(256) void k1_seg_offsets(const int* __restrict__ index,
                                                      int* __restrict__ seg_start,
                                                      const float* __restrict__ Wm,
                                                      unsigned short* __restrict__ wpk,
                                                      int N, int S) {
    if (blockIdx.x == 0) {
        for (int g = threadIdx.x; g < 2048; g += 256) {   // g=(kt*8+ct)*64+lane
            int lane = g & 63;
            int tile = g >> 6;
            int kt = tile >> 3, ct = tile & 7;
            int kbase = kt * 32 + (lane >> 4) * 8;
            int col   = ct * 16 + (lane & 15);
            #pragma unroll
            for (int j = 0; j < 8; ++j)
                wpk[g * 8 + j] = (unsigned short)bfc(Wm[(size_t)(kbase + j) * 128 + col]);
        }
    }
    int tid = blockIdx.x * blockDim.x + threadIdx.x;
    int stride = gridDim.x * blockDim.x;
    for (int i = tid; i < N; i += stride) {
        int cur  = index[i];
        int prev = (i == 0) ? -1 : index[i - 1];
        for (int s = prev + 1; s <= cur; ++s) seg_start[s] = i;
        if (i == N - 1) {
            for (int s = cur + 1; s <= S; ++s) seg_start[s] = N;
        }
    }
}

// K2: one wave per segment (oversubscribed grid -> HW self-balancing).
// R6-proven core; t now written as bf16 (16 B per lane<16).
__global__ __launch_bounds__(256) void k2_seg_softmax_pool(
    const float* __restrict__ x, const float* __restrict__ wt,
    const float* __restrict__ Wg, const float* __restrict__ bg,
    const float* __restrict__ pw_, const int* __restrict__ seg_start,
    unsigned short* __restrict__ t, float* __restrict__ sgate, int S) {
    int gwid = (int)((blockIdx.x * 256 + threadIdx.x) >> 6);
    if (gwid >= S) return;
    int lane = threadIdx.x & 63;
    int grp  = lane >> 4;        // which row of the 4-row step
    int pos  = lane & 15;        // feature slice [8*pos, 8*pos+8)

    int start = seg_start[gwid], end = seg_start[gwid + 1];

    if (start >= end) {          // empty segment: exact zeros
        if (lane < 16) {
            bf16x8 z = (bf16x8){0,0,0,0,0,0,0,0};
            *reinterpret_cast<bf16x8*>(t + (size_t)gwid * 128 + pos * 8) = z;
        }
        if (lane == 0) sgate[gwid] = 0.f;
        return;
    }

    float4 wg0 = *reinterpret_cast<const float4*>(Wg + pos * 8);
    float4 wg1 = *reinterpret_cast<const float4*>(Wg + pos * 8 + 4);
    float bgv = bg[0];
    float pw  = pw_[0];

    int nsteps = (end - start + 3) >> 2;
    int last   = end - 1;

    float4 a0, b0, a1, b1, a2, b2;
    float  w0, w1, w2;

    auto issue = [&](int s, float4& A, float4& B, float& Wv) {
        int r  = start + 4 * s + grp;
        int rc = (r < last) ? r : last;           // clamp: always valid
        const float* p = x + (size_t)rc * 128 + pos * 8;
        A  = *reinterpret_cast<const float4*>(p);
        B  = *reinterpret_cast<const float4*>(p + 4);
        Wv = wt[rc];
    };

    issue(0, a0, b0, w0);
    issue(1, a1, b1, w1);

    float mg = -INFINITY, ssum = 0.f;
    float acc[8];
    #pragma unroll
    for (int j = 0; j < 8; ++j) acc[j] = 0.f;

    for (int s = 0; s < nsteps; ++s) {
        issue(s + 2, a2, b2, w2);     // clamped beyond end: harmless L1 hit

        bool v = (start + 4 * s + grp) < end;
        float lw = fmaf(pw, __logf(w0), bgv);
        float p = a0.x*wg0.x + a0.y*wg0.y + a0.z*wg0.z + a0.w*wg0.w
                + b0.x*wg1.x + b0.y*wg1.y + b0.z*wg1.z + b0.w*wg1.w;
        p += __shfl_xor(p, 1);
        p += __shfl_xor(p, 2);
        p += __shfl_xor(p, 4);
        p += __shfl_xor(p, 8);
        float h = v ? (p + lw) : -1e30f;

        if (v && h > mg + 8.f) {          // defer-rescale: rarely taken
            float sc = __expf(mg - h);
            ssum *= sc;
            #pragma unroll
            for (int j = 0; j < 8; ++j) acc[j] *= sc;
            mg = h;
        }
        float e = v ? __expf(h - mg) : 0.f;   // bounded by e^8
        ssum += e;
        acc[0] += e * a0.x; acc[1] += e * a0.y; acc[2] += e * a0.z; acc[3] += e * a0.w;
        acc[4] += e * b0.x; acc[5] += e * b0.y; acc[6] += e * b0.z; acc[7] += e * b0.w;

        a0 = a1; b0 = b1; w0 = w1;
        a1 = a2; b1 = b2; w1 = w2;
    }

    #pragma unroll
    for (int off = 16; off <= 32; off <<= 1) {
        float mo = __shfl_xor(mg, off);
        float so = __shfl_xor(ssum, off);
        float ao[8];
        #pragma unroll
        for (int j = 0; j < 8; ++j) ao[j] = __shfl_xor(acc[j], off);
        float mc = fmaxf(mg, mo);
        float c1 = (mg > -1e37f) ? __expf(mg - mc) : 0.f;
        float c2 = (mo > -1e37f) ? __expf(mo - mc) : 0.f;
        ssum = ssum * c1 + so * c2;
        #pragma unroll
        for (int j = 0; j < 8; ++j) acc[j] = acc[j] * c1 + ao[j] * c2;
        mg = mc;
    }

    float inv = 1.f / (ssum + 1e-10f);
    if (lane < 16) {
        bf16x8 tv;
        #pragma unroll
        for (int j = 0; j < 8; ++j) tv[j] = bfc(acc[j] * inv);
        *reinterpret_cast<bf16x8*>(t + (size_t)gwid * 128 + pos * 8) = tv;
    }
    if (lane == 0) sgate[gwid] = ssum * inv;
}

// K3 (MFMA): out = t @ Wm + sgate (x) bm; t already bf16 -> direct A-frag load.
// A layout: row=lane&15, k=kt*32+(lane>>4)*8+j. C/D: col=lane&15,
// row=(lane>>4)*4+reg (m89-verified).
__global__ __launch_bounds__(256) void k3_mfma(
    const unsigned short* __restrict__ t, const unsigned short* __restrict__ wpk,
    const float* __restrict__ bm, const float* __restrict__ sgate,
    float* __restrict__ out, int S) {
    int wv = threadIdx.x >> 6, lane = threadIdx.x & 63;
    int r0 = blockIdx.x * 64 + wv * 16;
    int arow = r0 + (lane & 15);
    int koff = (lane >> 4) * 8;

    f32x4 acc[8];
    #pragma unroll
    for (int ct = 0; ct < 8; ++ct) acc[ct] = (f32x4){0.f, 0.f, 0.f, 0.f};

    #pragma unroll
    for (int kt = 0; kt < 4; ++kt) {
        bf16x8 af = *reinterpret_cast<const bf16x8*>(
            t + (size_t)arow * 128 + kt * 32 + koff);
        #pragma unroll
        for (int ct = 0; ct < 8; ++ct) {
            bf16x8 bf_ = *reinterpret_cast<const bf16x8*>(
                wpk + ((size_t)((kt * 8 + ct) * 64 + lane)) * 8);
            acc[ct] = __builtin_amdgcn_mfma_f32_16x16x32_bf16(af, bf_, acc[ct], 0, 0, 0);
        }
    }

    // epilogue: + sgate[row]*bm[col]; guard row < S on store
    float sgv[4];
    #pragma unroll
    for (int reg = 0; reg < 4; ++reg)
        sgv[reg] = sgate[r0 + (lane >> 4) * 4 + reg];   // OOB rows read ws pad (finite, discarded)
    int colb = lane & 15;
    #pragma unroll
    for (int ct = 0; ct < 8; ++ct) {
        float bmv = bm[ct * 16 + colb];
        #pragma unroll
        for (int reg = 0; reg < 4; ++reg) {
            int row = r0 + (lane >> 4) * 4 + reg;
            if (row < S)
                out[(size_t)row * 128 + ct * 16 + colb] = acc[ct][reg] + sgv[reg] * bmv;
        }
    }
}

extern "C" void kernel_launch(void* const* d_in, const int* in_sizes, int n_in,
                              void* d_out, int out_size, void* d_ws, size_t ws_size,
                              hipStream_t stream) {
    const float* x       = (const float*)d_in[0];
    const float* weights = (const float*)d_in[1];
    const float* Wg      = (const float*)d_in[2];
    const float* bg      = (const float*)d_in[3];
    const float* Wm      = (const float*)d_in[4];
    const float* bm      = (const float*)d_in[5];
    const float* pow_    = (const float*)d_in[6];
    const int*   index   = (const int*)d_in[7];
    float* out = (float*)d_out;

    int N = in_sizes[1];          // weights is [N,1]
    int S = out_size / 128;       // out is [S,128]

    // workspace layout
    char* ws = (char*)d_ws;
    int* seg_start = (int*)ws;                                  // (S+1) ints
    size_t off = (((size_t)(S + 1) * 4) + 255) & ~(size_t)255;
    float* sgate = (float*)(ws + off);                          // S floats (+pad read by K3)
    off += (((size_t)(S + 64) * 4) + 255) & ~(size_t)255;
    unsigned short* t = (unsigned short*)(ws + off);            // (S+64)*128 bf16
    off += (((size_t)(S + 64) * 128 * 2) + 255) & ~(size_t)255;
    unsigned short* wpk = (unsigned short*)(ws + off);          // 16384 bf16 (32 KB)

    k1_seg_offsets<<<2048, 256, 0, stream>>>(index, seg_start, Wm, wpk, N, S);
    k2_seg_softmax_pool<<<(S + 3) / 4, 256, 0, stream>>>(x, weights, Wg, bg, pow_,
                                                         seg_start, t, sgate, S);
    k3_mfma<<<(S + 63) / 64, 256, 0, stream>>>(t, wpk, bm, sgate, out, S);
}